// Round 10
// baseline (11442.600 us; speedup 1.0000x reference)
//
#include <hip/hip_runtime.h>
#include <cstdint>
#include <cstddef>

// ---------------------------------------------------------------------------
// PurifiedVAE persistent-RNN, round 16.
// enc: enc_kernel, 256 WGs = 8 chains (2 dir x 4 batch-quarters of 64 rows)
//      x 32 slices of 32 h-cols; 48 gate-cols LDS + 48 streamed COALESCED
//      from pre-transposed wbt (r15-proven, absmax bit-stable).
// dec: persist_kernel<1> r13-verbatim structure (proven).
// r16 CHANGES (both low-risk):
//  1. `nt` (non-temporal) added to all A-gather loads (enc EA, dec AISSUE_D):
//     A-data is single-use streaming; if sc0|sc1 loads allocate in L1/L2 they
//     evict the enc streamed-B working set (3.2 MB/XCD vs 4 MB L2) forcing B
//     back to LLC. nt prevents allocation; coherence (sc0 sc1) unchanged.
//     Pure hint -> zero correctness risk; tests the B-eviction theory.
//  2. prep restructured division-free: row-outer loops hoist the /1056,
//     /3072, /KE_DEC out of the per-element path (10M elements). Identical
//     values -> absmax unchanged; prep time ~2x down.
// Sync: per-WG one-shot flag slots (value = step+1), wave-parallel polling.
// ---------------------------------------------------------------------------

typedef _Float16 f16;
typedef _Float16 f16x8 __attribute__((ext_vector_type(8)));
typedef float f32x4 __attribute__((ext_vector_type(4)));

#define NB 256
#define NT 512
#define NI 12
#define NH 1024
#define NZ 128
#define NG 3072
#define KE_ENC 1056   // 1024 + 32 ext (x,1,pad)
#define KE_DEC 1184   // 1024 + 160 ext (x,1,pad,z128)
#define XK_ENC 32
#define XK_DEC 160
#define ZXP 40        // Zx row stride in halves

// wbt geometry (halves): per (dir,slice) 16*3072 chunk + 3*512 ext = 50688
#define WBT_PS 50688
#define WBT_EXT 49152

#define MFMA16(a, b, c) __builtin_amdgcn_mfma_f32_16x16x32_f16((a), (b), (c), 0, 0, 0)

// ---- workspace layout (bytes) ----
#define OFF_WENC  ((size_t)0)                              // 2*32*48*1056*2 = 6,488,064
#define OFF_WBT   (OFF_WENC + (size_t)2 * 32 * 48 * 1056 * 2)  // 2*32*50688*2 = 6,488,064
#define OFF_WMD   (OFF_WBT + (size_t)2 * 32 * WBT_PS * 2)
#define OFF_WNF   (OFF_WMD + (size_t)NG * KE_DEC * 2)
#define OFF_WNB   (OFF_WNF + (size_t)NH * XK_ENC * 2)
#define OFF_WND   (OFF_WNB + (size_t)NH * XK_ENC * 2)
#define OFF_WOUT  (OFF_WND + (size_t)NH * XK_DEC * 2)
#define OFF_HENC16 (OFF_WOUT + (size_t)16 * KE_ENC * 2)   // enc [2dir][2buf] / dec [4buf] of [NB*NH] f16
#define OFF_HF32   (OFF_HENC16 + (size_t)4 * NB * NH * 2) // [2 dir][NB*NH] f32
#define OFF_CTL    (OFF_HF32 + (size_t)2 * NB * NH * 4)   // dec flags (1 MB region)
#define OFF_H32D   (OFF_CTL + (size_t)2 * NB * NH * 2)    // [NB*NH] f32
#define OFF_Z32    (OFF_H32D + (size_t)NB * NH * 4)
#define OFF_Z16    (OFF_Z32 + (size_t)NB * NZ * 4)
#define OFF_FLG    (OFF_Z16 + (size_t)NB * NZ * 2)
#define N_FLG 204800          // enc uses first 131072 = [8][512][32]
#define N_FLGD 131072         // dec flags in CTL region: 4*512*64
#define WS_NEEDED (OFF_FLG + (size_t)N_FLG * 4)

// d_out element offsets (fp32): recon [256,512,12], mean [256,128], stddev [256,128]
#define OUT_MEAN (NB * NT * NI)
#define OUT_STD  (OUT_MEAN + NB * NZ)

// whole-wave flag poll: lanes watch nslots (power of 2) slots in parallel.
__device__ __forceinline__ void wave_spin(const unsigned* base, unsigned tgt,
                                          int lane, int nslots) {
    const unsigned* p = base + (lane & (nslots - 1));
    for (;;) {
        unsigned v = __hip_atomic_load(p, __ATOMIC_RELAXED, __HIP_MEMORY_SCOPE_AGENT);
        if (__all((int)(v == tgt))) break;
        __builtin_amdgcn_s_sleep(1);
    }
}

// counted vmcnt wait + scheduling fence (rule-18: MFMA may not hoist above).
#define PW(N) do { \
    asm volatile("s_waitcnt vmcnt(%0)" :: "n"(N) : "memory"); \
    __builtin_amdgcn_sched_barrier(0x387); \
} while (0)

// extended enc weight value at (gate-row c, k) -- same function as all rounds
__device__ __forceinline__ float enc_wval(int c, int k,
    const float* __restrict__ Whh, const float* __restrict__ Wih,
    const float* __restrict__ bih, const float* __restrict__ bhh) {
    if (k < NH) return Whh[(size_t)c * NH + k];
    const int e = k - NH;
    if (c < 2 * NH) {
        if (e < 12)  return Wih[c * 12 + e];
        if (e == 12) return bih[c] + bhh[c];
        return 0.f;
    }
    return (e == 12) ? bhh[c] : 0.f;
}

// ---------------------------------------------------------------------------
// prep: build enc compacted/transposed weights (wenc, wbt), dec extended
// weights, gi_n ext, Wout; zero h buffers + flags. r16: division-free
// row-outer loops (identical values to r15's element-stride version).
// ---------------------------------------------------------------------------
__global__ __launch_bounds__(256) void prep_kernel(
    const float* __restrict__ Whhf, const float* __restrict__ Wihf,
    const float* __restrict__ bihf, const float* __restrict__ bhhf,
    const float* __restrict__ Whhb, const float* __restrict__ Wihb,
    const float* __restrict__ bihb, const float* __restrict__ bhhb,
    const float* __restrict__ Wchh, const float* __restrict__ Wcih,
    const float* __restrict__ bcih, const float* __restrict__ bchh,
    const float* __restrict__ Wo,   const float* __restrict__ bo,
    f16* __restrict__ wenc, f16* __restrict__ wbt, f16* __restrict__ wmd,
    f16* __restrict__ wnf, f16* __restrict__ wnb, f16* __restrict__ wnd,
    f16* __restrict__ wout,
    f16* __restrict__ h16e0f, f16* __restrict__ h16e0b,
    unsigned* __restrict__ flgs, unsigned* __restrict__ flgd)
{
    const int tid = threadIdx.x;
    const int nb_ = gridDim.x;
    const int gsz = gridDim.x * blockDim.x;
    const int gid = blockIdx.x * blockDim.x + tid;

    // wenc: row-outer (3072 rows), element-inner (1056)
    for (int row = blockIdx.x; row < 2 * 32 * 48; row += nb_) {
        const int d = row / (32 * 48);
        const int rem = row - d * (32 * 48);
        const int s = rem / 48;
        const int r = rem - s * 48;
        const int c = (r >> 4) * NH + s * 32 + (r & 15);
        f16* dst = wenc + (size_t)row * 1056;
        if (d == 0)
            for (int k = tid; k < 1056; k += 256)
                dst[k] = (f16)enc_wval(c, k, Whhf, Wihf, bihf, bhhf);
        else
            for (int k = tid; k < 1056; k += 256)
                dst[k] = (f16)enc_wval(c, k, Whhb, Wihb, bihb, bhhb);
    }
    // wbt: chunk-row-outer (64 ds x 17 [16 chunks + ext]), bit-op inner
    for (int cr = blockIdx.x; cr < 64 * 17; cr += nb_) {
        const int ds = cr / 17;
        const int c = cr - ds * 17;
        const int d = ds >> 5, s = ds & 31;
        const float* Whh = d ? Whhb : Whhf;
        const float* Wih = d ? Wihb : Wihf;
        const float* bih = d ? bihb : bihf;
        const float* bhh = d ? bhhb : bhhf;
        f16* base = wbt + (size_t)ds * WBT_PS;
        if (c < 16) {
            for (int v = tid; v < 3072; v += 256) {
                const int g = v >> 10;
                const int w1 = v & 1023;
                const int kt2 = w1 >> 9;
                const int w2 = w1 & 511;
                const int l = w2 >> 3, e = w2 & 7;
                const int k = (c * 2 + kt2) * 32 + (l >> 4) * 8 + e;
                const int c_ = g * NH + s * 32 + 16 + (l & 15);
                base[c * 3072 + v] = (f16)enc_wval(c_, k, Whh, Wih, bih, bhh);
            }
        } else {
            for (int v = tid; v < 1536; v += 256) {
                const int g = v >> 9;
                const int w1 = v & 511;
                const int l = w1 >> 3, e = w1 & 7;
                const int k = 1024 + (l >> 4) * 8 + e;
                const int c_ = g * NH + s * 32 + 16 + (l & 15);
                base[WBT_EXT + v] = (f16)enc_wval(c_, k, Whh, Wih, bih, bhh);
            }
        }
    }
    // wmd: row-outer (3072 rows x 1184)
    for (int c = blockIdx.x; c < NG; c += nb_) {
        f16* dst = wmd + (size_t)c * KE_DEC;
        for (int k = tid; k < KE_DEC; k += 256) {
            float v;
            if (k < NH) v = Wchh[c * NH + k];
            else {
                const int e = k - NH;
                if (c < 2 * NH) {
                    if (e < 12)       v = Wcih[c * 140 + e];
                    else if (e == 12) v = bcih[c] + bchh[c];
                    else if (e < 32)  v = 0.f;
                    else              v = Wcih[c * 140 + 12 + (e - 32)];
                } else v = (e == 12) ? bchh[c] : 0.f;
            }
            dst[k] = (f16)v;
        }
    }
    for (int idx = gid; idx < NH * XK_ENC; idx += gsz) {
        const int j = idx >> 5, e = idx & 31;
        const int c = 2 * NH + j;
        float vf, vb;
        if (e < 12)       { vf = Wihf[c * 12 + e]; vb = Wihb[c * 12 + e]; }
        else if (e == 12) { vf = bihf[c]; vb = bihb[c]; }
        else              { vf = 0.f; vb = 0.f; }
        wnf[idx] = (f16)vf; wnb[idx] = (f16)vb;
    }
    for (int idx = gid; idx < NH * XK_DEC; idx += gsz) {
        const int j = idx / XK_DEC, e = idx - j * XK_DEC;
        const int c = 2 * NH + j;
        float v;
        if (e < 12)       v = Wcih[c * 140 + e];
        else if (e == 12) v = bcih[c];
        else if (e < 32)  v = 0.f;
        else              v = Wcih[c * 140 + 12 + (e - 32)];
        wnd[idx] = (f16)v;
    }
    for (int idx = gid; idx < 16 * KE_ENC; idx += gsz) {
        const int i = idx / KE_ENC, k = idx - i * KE_ENC;
        float v = 0.f;
        if (i < 12) {
            if (k < NH) v = Wo[i * NH + k];
            else if (k == NH + 12) v = bo[i];
        }
        wout[idx] = (f16)v;
    }
    for (int idx = gid; idx < NB * NH; idx += gsz) {
        h16e0f[idx] = (f16)0.f; h16e0b[idx] = (f16)0.f;
    }
    for (int idx = gid; idx < N_FLG; idx += gsz) flgs[idx] = 0u;
    for (int idx = gid; idx < N_FLGD; idx += gsz) flgd[idx] = 0u;
}

// ---------------------------------------------------------------------------
// enc_kernel: 256 WGs = 8 chains x 32 slices. chain = bid>>5 (dir = chain>>2,
// quarter = chain&3 -> 64-row panel); slice = bid&31 -> 32 h-cols (96 gate-
// cols: 48 in LDS + 48 streamed COALESCED from wbt). Wave owns 16 rows; A
// full-K register gather (sc0 sc1 nt); B per-step from L2 in fragment order.
// ---------------------------------------------------------------------------
__global__ __launch_bounds__(256, 1) void enc_kernel(
    const float* __restrict__ x,
    const f16* __restrict__ wenc, const f16* __restrict__ wbt,
    const f16* __restrict__ wnF, const f16* __restrict__ wnB_,
    f16* __restrict__ hbuf,          // [dir][2][NB*NH]
    float* __restrict__ hf32,        // [dir][NB*NH]
    unsigned* __restrict__ flg)      // [8][512][32]
{
    constexpr int KE  = KE_ENC;
    constexpr int KEP = KE + 8;

    __shared__ f16 Wlds[48 * KEP];   // gates r,z,n for h-cols j0..j0+15 (102 KB)
    __shared__ f16 wnlds[32 * ZXP];  // gi_n ext weights, 32 h-cols (2.5 KB)
    __shared__ f16 Zx[64 * ZXP];     // per-step x+bias A-ext rows (5.1 KB)

    const int tid = threadIdx.x;
    const int bid = blockIdx.x;
    const int w = tid >> 6, lane = tid & 63;
    const int lr = lane & 15, quad = lane >> 4;

    const int chain = bid >> 5;          // 0..7
    const int slice = bid & 31;
    const int dir = chain >> 2;
    const int m0 = (chain & 3) * 64;
    const int j0 = slice * 32;
    const int RB = m0 + (w << 4);        // wave row base (16 rows)

    const f16* wn = dir ? wnB_ : wnF;
    f16* hb0 = hbuf + (size_t)dir * 2 * NB * NH;
    const f16* wenc_s = wenc + (size_t)(dir * 32 + slice) * 48 * 1056;
    const f16* wbt_s  = wbt  + (size_t)(dir * 32 + slice) * WBT_PS;

    // one-time LDS loads
    constexpr int KQ = KE / 8;           // 132
    for (int u = tid; u < 48 * KQ; u += 256) {
        const int r = u / KQ, kk = u - r * KQ;
        *(uint4*)&Wlds[r * KEP + kk * 8] =
            *(const uint4*)(wenc_s + (size_t)r * 1056 + kk * 8);
    }
    for (int u = tid; u < 32 * 4; u += 256) {      // gi_n ext, rows = h-col j0+r
        const int r = u >> 2, kk = u & 3;
        *(uint4*)&wnlds[r * ZXP + kk * 8] =
            *(const uint4*)(wn + (size_t)(j0 + r) * XK_ENC + kk * 8);
    }
    for (int u = tid; u < 64 * ZXP / 8; u += 256)
        *(uint4*)&Zx[u * 8] = make_uint4(0u, 0u, 0u, 0u);
    __syncthreads();

    // streamed cols' ext fragments -> registers (loaded once)
    f16x8 bext0 = *(const f16x8*)(wbt_s + WBT_EXT + 0 * 512 + lane * 8);
    f16x8 bext1 = *(const f16x8*)(wbt_s + WBT_EXT + 1 * 512 + lane * 8);
    f16x8 bext2 = *(const f16x8*)(wbt_s + WBT_EXT + 2 * 512 + lane * 8);

    // fp32 h master: [col-set][r]; rows RB+quad*4+r, cols j0+cs*16+lr
    float hmast[2][4];
#pragma unroll
    for (int cs = 0; cs < 2; ++cs)
#pragma unroll
        for (int r = 0; r < 4; ++r) hmast[cs][r] = 0.f;

    unsigned* myflg = flg + (size_t)chain * 512 * 32;

    // per-lane coalesced B base (chunk region of wbt)
    const char* vbB = (const char*)wbt_s + lane * 16;

// A chunk c = k-tiles 2c,2c+1 (2 loads, sc0 sc1 nt: LLC-coherent, no L1/L2 alloc)
#define EA(c) do { \
    asm volatile( \
        "global_load_dwordx4 %0, %2, off offset:%3 sc0 sc1 nt\n\t" \
        "global_load_dwordx4 %1, %2, off offset:%4 sc0 sc1 nt" \
        : "=&v"(av[(c) & 7][0]), "=&v"(av[(c) & 7][1]) \
        : "v"(ga0), "n"((c) * 128), "n"((c) * 128 + 64) \
        : "memory"); \
} while (0)
// B chunk c: 6 COALESCED cached loads in fragment order; bv[s][g*2+kt2]
#define EB(c) do { \
    asm volatile( \
        "global_load_dwordx4 %0, %6, off offset:0\n\t" \
        "global_load_dwordx4 %1, %6, off offset:1024\n\t" \
        "global_load_dwordx4 %2, %6, off offset:2048\n\t" \
        "global_load_dwordx4 %3, %6, off offset:3072\n\t" \
        "global_load_dwordx4 %4, %7, off offset:1024\n\t" \
        "global_load_dwordx4 %5, %7, off offset:2048" \
        : "=&v"(bv[(c) & 3][0]), "=&v"(bv[(c) & 3][1]), \
          "=&v"(bv[(c) & 3][2]), "=&v"(bv[(c) & 3][3]), \
          "=&v"(bv[(c) & 3][4]), "=&v"(bv[(c) & 3][5]) \
        : "v"(vbB + (size_t)(c) * 6144), "v"(vbB + (size_t)(c) * 6144 + 3072) \
        : "memory"); \
} while (0)
#define ECONS(c) do { \
    _Pragma("unroll") \
    for (int kt2_ = 0; kt2_ < 2; ++kt2_) { \
        const int ktg_ = (c) * 2 + kt2_; \
        const f16x8 a_ = av[(c) & 7][kt2_]; \
        _Pragma("unroll") \
        for (int g_ = 0; g_ < 3; ++g_) { \
            const f16x8 bl_ = *(const f16x8*)(&Wlds[(g_ * 16 + lr) * KEP + ktg_ * 32 + (quad << 3)]); \
            acc0[g_] = MFMA16(a_, bl_, acc0[g_]); \
            acc1[g_] = MFMA16(a_, bv[(c) & 3][g_ * 2 + kt2_], acc1[g_]); \
        } \
    } \
} while (0)

#pragma unroll 1
    for (int t = 0; t < NT; ++t) {
        // stage per-step A-ext rows (x_t, bias 1 at e==12) for the 64 rows
        if (tid < 64) {
            f16 rowv[16];
            const int b_ = m0 + tid;
            const int tx = dir ? (NT - 1 - t) : t;
            const float4* xr = (const float4*)(x + ((size_t)b_ * NT + tx) * NI);
            const float4 x0 = xr[0], x1 = xr[1], x2 = xr[2];
            rowv[0] = (f16)x0.x; rowv[1] = (f16)x0.y; rowv[2] = (f16)x0.z; rowv[3] = (f16)x0.w;
            rowv[4] = (f16)x1.x; rowv[5] = (f16)x1.y; rowv[6] = (f16)x1.z; rowv[7] = (f16)x1.w;
            rowv[8] = (f16)x2.x; rowv[9] = (f16)x2.y; rowv[10] = (f16)x2.z; rowv[11] = (f16)x2.w;
            rowv[12] = (f16)1.f; rowv[13] = (f16)0.f; rowv[14] = (f16)0.f; rowv[15] = (f16)0.f;
            *(uint4*)&Zx[tid * ZXP]     = *(const uint4*)&rowv[0];
            *(uint4*)&Zx[tid * ZXP + 8] = *(const uint4*)&rowv[8];
        }
        // wait for step t-1 completion of all 32 slices (wave 0 polls)
        if (t > 0 && tid < 64)
            wave_spin(myflg + (size_t)(t - 1) * 32, (unsigned)t, lane, 32);
        __syncthreads();

        const f16* hcur = hb0 + (size_t)(t & 1) * (NB * NH);
        const char* ga0 = (const char*)(hcur + (size_t)(RB + lr) * NH) + (quad << 4);

        f32x4 acc0[3], acc1[3];
#pragma unroll
        for (int g = 0; g < 3; ++g) {
            f32x4 zv = {0.f, 0.f, 0.f, 0.f};
            acc0[g] = zv; acc1[g] = zv;
        }
        f32x4 accn0 = {0.f, 0.f, 0.f, 0.f}, accn1 = {0.f, 0.f, 0.f, 0.f};

        f16x8 av[8][2];
        f16x8 bv[4][6];
        // interleaved A/B counted-vmcnt ladder (r14/r15-verified schedule):
        EA(0); EA(1); EA(2); EA(3); EA(4);
        EB(0); EB(1); EB(2);
        PW(12); EA(5);  EB(3);  ECONS(0);
        PW(14); EA(6);  EB(4);  ECONS(1);
        PW(16); EA(7);  EB(5);  ECONS(2);
        PW(16); EA(8);  EB(6);  ECONS(3);
        PW(16); EA(9);  EB(7);  ECONS(4);
        PW(16); EA(10); EB(8);  ECONS(5);
        PW(16); EA(11); EB(9);  ECONS(6);
        PW(16); EA(12); EB(10); ECONS(7);
        PW(16); EA(13); EB(11); ECONS(8);
        PW(16); EA(14); EB(12); ECONS(9);
        PW(16); EA(15); EB(13); ECONS(10);
        PW(16); EB(14); ECONS(11);
        PW(14); EB(15); ECONS(12);
        PW(12); ECONS(13);
        PW(6);  ECONS(14);
        PW(0);  ECONS(15);

        // ext k-tile (kt=32): A = Zx (x,bias); B from Wlds / bext / wnlds
        {
            const f16x8 a0 = *(const f16x8*)(&Zx[((w << 4) + lr) * ZXP + (quad << 3)]);
            {
                const f16x8 bl = *(const f16x8*)(&Wlds[(0 * 16 + lr) * KEP + 1024 + (quad << 3)]);
                acc0[0] = MFMA16(a0, bl, acc0[0]);
                acc1[0] = MFMA16(a0, bext0, acc1[0]);
            }
            {
                const f16x8 bl = *(const f16x8*)(&Wlds[(1 * 16 + lr) * KEP + 1024 + (quad << 3)]);
                acc0[1] = MFMA16(a0, bl, acc0[1]);
                acc1[1] = MFMA16(a0, bext1, acc1[1]);
            }
            {
                const f16x8 bl = *(const f16x8*)(&Wlds[(2 * 16 + lr) * KEP + 1024 + (quad << 3)]);
                acc0[2] = MFMA16(a0, bl, acc0[2]);
                acc1[2] = MFMA16(a0, bext2, acc1[2]);
            }
            const f16x8 bn0 = *(const f16x8*)(&wnlds[lr * ZXP + (quad << 3)]);
            accn0 = MFMA16(a0, bn0, accn0);
            const f16x8 bn1 = *(const f16x8*)(&wnlds[(16 + lr) * ZXP + (quad << 3)]);
            accn1 = MFMA16(a0, bn1, accn1);
        }

        // gate combine + h update, both col-sets; packed dword write-through
        f16* hnext = hb0 + (size_t)((t + 1) & 1) * (NB * NH);
#pragma unroll
        for (int cs = 0; cs < 2; ++cs) {
#pragma unroll
            for (int r = 0; r < 4; ++r) {
                const float rr  = cs ? acc1[0][r] : acc0[0][r];
                const float zz  = cs ? acc1[1][r] : acc0[1][r];
                const float ghn = cs ? acc1[2][r] : acc0[2][r];
                const float gin = cs ? accn1[r]   : accn0[r];
                const float rg = 1.f / (1.f + __expf(-rr));
                const float zg = 1.f / (1.f + __expf(-zz));
                const float nv = gin + rg * ghn;
                const float e2 = __expf(2.f * nv);
                const float th = 1.f - 2.f / (e2 + 1.f);   // tanh, inf-safe
                const float hn = (1.f - zg) * th + zg * hmast[cs][r];
                hmast[cs][r] = hn;
                const unsigned hv =
                    (unsigned)__builtin_bit_cast(unsigned short, (f16)hn);
                const unsigned ov = (unsigned)__shfl_xor((int)hv, 1, 64);
                if (!(lr & 1)) {
                    const int row = RB + quad * 4 + r;
                    __hip_atomic_store(
                        (unsigned*)&hnext[(size_t)row * NH + j0 + cs * 16 + lr],
                        hv | (ov << 16),
                        __ATOMIC_RELAXED, __HIP_MEMORY_SCOPE_AGENT);
                }
            }
        }
        __syncthreads();   // vmcnt(0) drain of all waves' stores before flag
        if (tid == 0)
            __hip_atomic_store(myflg + (size_t)t * 32 + slice, (unsigned)(t + 1),
                               __ATOMIC_RELAXED, __HIP_MEMORY_SCOPE_AGENT);
    }
#undef EA
#undef EB
#undef ECONS

    // final fp32 h for heads1
    {
        float* hdst = hf32 + (size_t)dir * NB * NH;
#pragma unroll
        for (int cs = 0; cs < 2; ++cs)
#pragma unroll
            for (int r = 0; r < 4; ++r) {
                const int row = RB + quad * 4 + r;
                hdst[(size_t)row * NH + j0 + cs * 16 + lr] = hmast[cs][r];
            }
    }
}

// ---------------------------------------------------------------------------
// persist_kernel<MODE>: r13-verbatim structure; only MODE=1 (decoder) runs.
// dec: grid 256 = 4 chains (64 batch rows) x 64 slices; slice-0 WGs fold the
// sigmoid out-head into the gather (recon[t-1] at step t; epilogue t=511).
// r16: A-loads gain `nt` (cache-allocation hint only).
// ---------------------------------------------------------------------------
template<int MODE>
__global__ __launch_bounds__(256, 1) void persist_kernel(
    const float* __restrict__ x,
    const f16* __restrict__ wmF, const f16* __restrict__ wmB_,
    const f16* __restrict__ wnF, const f16* __restrict__ wnB_,
    const f16* __restrict__ wout, const f16* __restrict__ z16,
    f16* __restrict__ hbuf,          // dec: [4][NB*NH]
    float* __restrict__ hf32,
    const float* __restrict__ h32i,  // dec initial master (heads2)
    float* __restrict__ dout,
    unsigned* __restrict__ flg)      // [4][512][64]
{
    constexpr int KE  = MODE ? KE_DEC : KE_ENC;
    constexpr int KEP = KE + 8;
    constexpr int XK  = MODE ? XK_DEC : XK_ENC;
    constexpr int XKP = XK + 8;
    constexpr int NZT = MODE ? 4 : 0;   // z-register A k-tiles
    constexpr int NRT = MODE ? 1 : 2;   // row-tiles per wave
    constexpr int MROWS = MODE ? 64 : 128;  // panel rows per chain

    __shared__ f16 Wlds[48 * KEP];
    __shared__ f16 Zx[MROWS * ZXP];
    __shared__ f16 wnlds[16 * XKP];
    __shared__ f16 wolds[MODE ? 16 * 1064 : 8];  // dec: Wout (slice-0 only)

    const int tid = threadIdx.x;
    const int bid = blockIdx.x;
    const int w = tid >> 6, lane = tid & 63;
    const int lr = lane & 15, quad = lane >> 4;

    const int chain = bid >> 6;                 // 0..3
    const int slice = bid & 63;
    const int dir = MODE ? 0 : (chain >> 1);
    const int m0 = MODE ? chain * 64 : (chain & 1) * 128;
    const int j0 = slice * 16;
    const bool outw = (MODE == 1) && (slice == 0);
    const int RB = m0 + (MODE ? (w << 4) : (w << 5));

    const f16* wm = (MODE == 0 && dir) ? wmB_ : wmF;
    const f16* wn = (MODE == 0 && dir) ? wnB_ : wnF;
    f16* hb0 = hbuf + (MODE ? (size_t)0 : (size_t)dir * 2 * NB * NH);
    constexpr int BMSK = MODE ? 3 : 1;

    constexpr int KQ = KE / 8;
    for (int u = tid; u < 48 * KQ; u += 256) {
        const int r = u / KQ, kk = u - r * KQ;
        const int c = (r >> 4) * NH + j0 + (r & 15);
        *(uint4*)&Wlds[r * KEP + kk * 8] = *(const uint4*)(wm + (size_t)c * KE + kk * 8);
    }
    constexpr int XQ = XK / 8;
    for (int u = tid; u < 16 * XQ; u += 256) {
        const int r = u / XQ, kk = u - r * XQ;
        *(uint4*)&wnlds[r * XKP + kk * 8] =
            *(const uint4*)(wn + (size_t)(j0 + r) * XK + kk * 8);
    }
    if (outw) {
        for (int u = tid; u < 16 * 132; u += 256) {
            const int r = u / 132, kk = u - r * 132;
            *(uint4*)&wolds[r * 1064 + kk * 8] =
                *(const uint4*)(wout + (size_t)r * KE_ENC + kk * 8);
        }
    }
    for (int u = tid; u < MROWS * ZXP / 8; u += 256)
        *(uint4*)&Zx[u * 8] = make_uint4(0u, 0u, 0u, 0u);
    __syncthreads();

    float hmast[2][4];
    f16x8 azr[2][NZT ? NZT : 1];
#pragma unroll
    for (int rt = 0; rt < NRT; ++rt)
#pragma unroll
        for (int r = 0; r < 4; ++r)
            hmast[rt][r] = MODE
                ? h32i[(size_t)(RB + rt * 16 + quad * 4 + r) * NH + j0 + lr]
                : 0.f;
    if (MODE) {
#pragma unroll
        for (int rt = 0; rt < NRT; ++rt)
#pragma unroll
            for (int zt = 0; zt < NZT; ++zt)
                azr[rt][zt] = *(const f16x8*)(z16 +
                    (size_t)(RB + rt * 16 + lr) * NZ + zt * 32 + (quad << 3));
    }
    f16x8 ax;   // out-head A-ext: 1.0 at e==12
#pragma unroll
    for (int j = 0; j < 8; ++j) ax[j] = (f16)0.f;
    if (quad == 1) ax[4] = (f16)1.f;

    unsigned* myflg = flg + (size_t)chain * 512 * 64;

#define AISSUE_D(c) do { \
    asm volatile( \
        "global_load_dwordx4 %0, %2, off offset:%3 sc0 sc1 nt\n\t" \
        "global_load_dwordx4 %1, %2, off offset:%4 sc0 sc1 nt" \
        : "=&v"(av[(c)][0]), "=&v"(av[(c)][1]) \
        : "v"(ga0), "n"((c) * 128), "n"((c) * 128 + 64) \
        : "memory"); \
} while (0)
#define PCONS_D(c) do { \
    _Pragma("unroll") \
    for (int kt2_ = 0; kt2_ < 2; ++kt2_) { \
        const f16x8 a0_ = av[(c)][kt2_]; \
        _Pragma("unroll") \
        for (int g_ = 0; g_ < 3; ++g_) { \
            const f16x8 b_ = *(const f16x8*)(&Wlds[(g_ * 16 + lr) * KEP + ((c) * 2 + kt2_) * 32 + (quad << 3)]); \
            acc[g_][0] = MFMA16(a0_, b_, acc[g_][0]); \
        } \
        if (outw) { \
            const f16x8 bo_ = *(const f16x8*)(&wolds[lr * 1064 + ((c) * 2 + kt2_) * 32 + (quad << 3)]); \
            accq = MFMA16(a0_, bo_, accq); \
        } \
    } \
} while (0)
#define OCONSQ(c) do { \
    _Pragma("unroll") \
    for (int kt2_ = 0; kt2_ < 2; ++kt2_) { \
        const f16x8 bo_ = *(const f16x8*)(&wolds[lr * 1064 + ((c) * 2 + kt2_) * 32 + (quad << 3)]); \
        accq = MFMA16(av[(c)][kt2_], bo_, accq); \
    } \
} while (0)

#pragma unroll 1
    for (int t = 0; t < NT; ++t) {
        if (tid < MROWS) {
            f16 rowv[16];
            if (MODE == 1 && t == 0) {
#pragma unroll
                for (int e = 0; e < 12; ++e) rowv[e] = (f16)((e == NI - 1) ? 1.f : 0.f);
            } else {
                const int b_ = m0 + tid;
                const int tx = MODE ? (t - 1) : (dir ? (NT - 1 - t) : t);
                const float4* xr = (const float4*)(x + ((size_t)b_ * NT + tx) * NI);
                const float4 x0 = xr[0], x1 = xr[1], x2 = xr[2];
                rowv[0] = (f16)x0.x; rowv[1] = (f16)x0.y; rowv[2] = (f16)x0.z; rowv[3] = (f16)x0.w;
                rowv[4] = (f16)x1.x; rowv[5] = (f16)x1.y; rowv[6] = (f16)x1.z; rowv[7] = (f16)x1.w;
                rowv[8] = (f16)x2.x; rowv[9] = (f16)x2.y; rowv[10] = (f16)x2.z; rowv[11] = (f16)x2.w;
            }
            rowv[12] = (f16)1.f; rowv[13] = (f16)0.f; rowv[14] = (f16)0.f; rowv[15] = (f16)0.f;
            *(uint4*)&Zx[tid * ZXP]     = *(const uint4*)&rowv[0];
            *(uint4*)&Zx[tid * ZXP + 8] = *(const uint4*)&rowv[8];
        }
        if (t > 0 && tid < 64)
            wave_spin(myflg + (size_t)(t - 1) * 64, (unsigned)t, lane, 64);
        __syncthreads();

        const f16* hcur = hb0 + (size_t)(t & BMSK) * (NB * NH);
        const char* ga0 = (const char*)(hcur +
            (size_t)(RB + lr) * NH) + (quad << 4);

        f32x4 acc[3][2], accn[2];
#pragma unroll
        for (int g = 0; g < 3; ++g)
#pragma unroll
            for (int rt = 0; rt < 2; ++rt) { f32x4 zv = {0.f,0.f,0.f,0.f}; acc[g][rt] = zv; }
        { f32x4 zv = {0.f,0.f,0.f,0.f}; accn[0] = zv; accn[1] = zv; }
        f32x4 accq = {0.f, 0.f, 0.f, 0.f};

        {
            f16x8 av[16][2];
            AISSUE_D(0);  AISSUE_D(1);  AISSUE_D(2);  AISSUE_D(3);
            AISSUE_D(4);  AISSUE_D(5);  AISSUE_D(6);  AISSUE_D(7);
            AISSUE_D(8);  AISSUE_D(9);  AISSUE_D(10); AISSUE_D(11);
            AISSUE_D(12); AISSUE_D(13); AISSUE_D(14); AISSUE_D(15);
            PW(30); PCONS_D(0);
            PW(28); PCONS_D(1);
            PW(26); PCONS_D(2);
            PW(24); PCONS_D(3);
            PW(22); PCONS_D(4);
            PW(20); PCONS_D(5);
            PW(18); PCONS_D(6);
            PW(16); PCONS_D(7);
            PW(14); PCONS_D(8);
            PW(12); PCONS_D(9);
            PW(10); PCONS_D(10);
            PW(8);  PCONS_D(11);
            PW(6);  PCONS_D(12);
            PW(4);  PCONS_D(13);
            PW(2);  PCONS_D(14);
            PW(0);  PCONS_D(15);
        }

#pragma unroll
        for (int xt = 0; xt <= NZT; ++xt) {
            const int kt = 32 + xt;
            f16x8 a0, a1;
            if (xt == 0) {
                a0 = *(const f16x8*)(&Zx[((MODE ? (w << 4) : (w << 5)) + lr) * ZXP + (quad << 3)]);
                if (MODE == 0)
                    a1 = *(const f16x8*)(&Zx[((w << 5) + 16 + lr) * ZXP + (quad << 3)]);
            } else { a0 = azr[0][xt - 1]; if (NRT > 1) a1 = azr[1][xt - 1]; }
#pragma unroll
            for (int g = 0; g < 3; ++g) {
                f16x8 b = *(const f16x8*)(&Wlds[(g * 16 + lr) * KEP + kt * 32 + (quad << 3)]);
                acc[g][0] = MFMA16(a0, b, acc[g][0]);
                if (NRT > 1) acc[g][1] = MFMA16(a1, b, acc[g][1]);
            }
            f16x8 bn = *(const f16x8*)(&wnlds[lr * XKP + xt * 32 + (quad << 3)]);
            accn[0] = MFMA16(a0, bn, accn[0]);
            if (NRT > 1) accn[1] = MFMA16(a1, bn, accn[1]);
        }

        if (outw) {
            const f16x8 bo_ = *(const f16x8*)(&wolds[lr * 1064 + 1024 + (quad << 3)]);
            accq = MFMA16(ax, bo_, accq);
            if (t >= 1 && lr < NI) {
#pragma unroll
                for (int r = 0; r < 4; ++r) {
                    const int b_ = RB + quad * 4 + r;
                    dout[(size_t)b_ * (NT * NI) + (t - 1) * NI + lr] =
                        1.f / (1.f + __expf(-accq[r]));
                }
            }
        }

        f16* hnext = hb0 + (size_t)((t + 1) & BMSK) * (NB * NH);
#pragma unroll
        for (int rt = 0; rt < NRT; ++rt) {
#pragma unroll
            for (int r = 0; r < 4; ++r) {
                const float rr  = acc[0][rt][r];
                const float zz  = acc[1][rt][r];
                const float ghn = acc[2][rt][r];
                const float gin = accn[rt][r];
                const float rg = 1.f / (1.f + __expf(-rr));
                const float zg = 1.f / (1.f + __expf(-zz));
                const float nv = gin + rg * ghn;
                const float e2 = __expf(2.f * nv);
                const float th = 1.f - 2.f / (e2 + 1.f);
                const float hn = (1.f - zg) * th + zg * hmast[rt][r];
                hmast[rt][r] = hn;
                const unsigned hv =
                    (unsigned)__builtin_bit_cast(unsigned short, (f16)hn);
                const unsigned ov = (unsigned)__shfl_xor((int)hv, 1, 64);
                if (!(lr & 1)) {
                    const int row = RB + rt * 16 + quad * 4 + r;
                    __hip_atomic_store(
                        (unsigned*)&hnext[(size_t)row * NH + j0 + lr],
                        hv | (ov << 16),
                        __ATOMIC_RELAXED, __HIP_MEMORY_SCOPE_AGENT);
                }
            }
        }
        __syncthreads();
        if (tid == 0)
            __hip_atomic_store(myflg + (size_t)t * 64 + slice, (unsigned)(t + 1),
                               __ATOMIC_RELAXED, __HIP_MEMORY_SCOPE_AGENT);
    }

    if (MODE == 1 && outw) {
        if (tid < 64)
            wave_spin(myflg + (size_t)511 * 64, 512u, lane, 64);
        __syncthreads();
        const f16* hc = hb0 + (size_t)(512 & BMSK) * (NB * NH);
        const char* ga0 = (const char*)(hc + (size_t)(RB + lr) * NH) + (quad << 4);
        f32x4 accq = {0.f, 0.f, 0.f, 0.f};
        f16x8 av[16][2];
        AISSUE_D(0);  AISSUE_D(1);  AISSUE_D(2);  AISSUE_D(3);
        AISSUE_D(4);  AISSUE_D(5);  AISSUE_D(6);  AISSUE_D(7);
        AISSUE_D(8);  AISSUE_D(9);  AISSUE_D(10); AISSUE_D(11);
        AISSUE_D(12); AISSUE_D(13); AISSUE_D(14); AISSUE_D(15);
        PW(30); OCONSQ(0);
        PW(28); OCONSQ(1);
        PW(26); OCONSQ(2);
        PW(24); OCONSQ(3);
        PW(22); OCONSQ(4);
        PW(20); OCONSQ(5);
        PW(18); OCONSQ(6);
        PW(16); OCONSQ(7);
        PW(14); OCONSQ(8);
        PW(12); OCONSQ(9);
        PW(10); OCONSQ(10);
        PW(8);  OCONSQ(11);
        PW(6);  OCONSQ(12);
        PW(4);  OCONSQ(13);
        PW(2);  OCONSQ(14);
        PW(0);  OCONSQ(15);
        {
            const f16x8 bo_ = *(const f16x8*)(&wolds[lr * 1064 + 1024 + (quad << 3)]);
            accq = MFMA16(ax, bo_, accq);
        }
        if (lr < NI) {
#pragma unroll
            for (int r = 0; r < 4; ++r) {
                const int b_ = RB + quad * 4 + r;
                dout[(size_t)b_ * (NT * NI) + 511 * NI + lr] =
                    1.f / (1.f + __expf(-accq[r]));
            }
        }
    }
#undef AISSUE_D
#undef PCONS_D
#undef OCONSQ
}

// ---------------------------------------------------------------------------
// heads1: mean / stddev / z from final encoder states (fp32 exact).
// ---------------------------------------------------------------------------
__global__ __launch_bounds__(256) void heads1_kernel(
    const float* __restrict__ hf, const float* __restrict__ hb,
    const float* __restrict__ Wmu, const float* __restrict__ bmu,
    const float* __restrict__ Wvar, const float* __restrict__ bvar,
    const float* __restrict__ noise,
    float* __restrict__ dout, float* __restrict__ z32, f16* __restrict__ z16)
{
    const int tid = threadIdx.x;
    const int b  = ((int)blockIdx.x >> 3) * 16 + (tid >> 4);
    const int zi = ((int)blockIdx.x & 7) * 16 + (tid & 15);
    const float4* h4 = (const float4*)(hf + (size_t)b * NH);
    const float4* g4 = (const float4*)(hb + (size_t)b * NH);
    const float4* m4 = (const float4*)(Wmu + (size_t)zi * (2 * NH));
    const float4* v4 = (const float4*)(Wvar + (size_t)zi * (2 * NH));
    float sm_ = 0.f, sv = 0.f;
    for (int k = 0; k < NH / 4; ++k) {
        const float4 h = h4[k], a = m4[k], c = v4[k];
        sm_ += h.x * a.x + h.y * a.y + h.z * a.z + h.w * a.w;
        sv  += h.x * c.x + h.y * c.y + h.z * c.z + h.w * c.w;
    }
    for (int k = 0; k < NH / 4; ++k) {
        const float4 h = g4[k], a = m4[NH / 4 + k], c = v4[NH / 4 + k];
        sm_ += h.x * a.x + h.y * a.y + h.z * a.z + h.w * a.w;
        sv  += h.x * c.x + h.y * c.y + h.z * c.z + h.w * c.w;
    }
    const float mean = sm_ + bmu[zi];
    const float lv   = sv + bvar[zi];
    const float sd   = __expf(0.5f * lv);
    const float zv   = mean + sd * noise[(size_t)b * NZ + zi];
    dout[OUT_MEAN + (size_t)b * NZ + zi] = mean;
    dout[OUT_STD  + (size_t)b * NZ + zi] = sd;
    z32[b * NZ + zi] = zv;
    z16[b * NZ + zi] = (f16)zv;
}

// ---------------------------------------------------------------------------
// heads2: h_dec0 = tanh(z @ W_init^T + b_init) -> fp32 master + h16 buffer 0.
// ---------------------------------------------------------------------------
__global__ __launch_bounds__(256) void heads2_kernel(
    const float* __restrict__ z32, const float* __restrict__ Winit,
    const float* __restrict__ binit,
    float* __restrict__ h32d, f16* __restrict__ h16d)
{
    __shared__ float Wi[16 * NZ];
    __shared__ float bi[16];
    const int tid = threadIdx.x;
    const int jb = blockIdx.x;
    for (int f = tid; f < 16 * NZ; f += 256)
        Wi[f] = Winit[(size_t)(jb * 16 + (f >> 7)) * NZ + (f & 127)];
    if (tid < 16) bi[tid] = binit[jb * 16 + tid];
    __syncthreads();
    const int b = tid;
    const float4* z4 = (const float4*)(z32 + (size_t)b * NZ);
    float4 zr[NZ / 4];
#pragma unroll
    for (int k = 0; k < NZ / 4; ++k) zr[k] = z4[k];
    for (int hj = 0; hj < 16; ++hj) {
        const float4* w4 = (const float4*)(Wi + hj * NZ);
        float s = bi[hj];
#pragma unroll
        for (int k = 0; k < NZ / 4; ++k) {
            const float4 a = w4[k], z = zr[k];
            s += z.x * a.x + z.y * a.y + z.z * a.z + z.w * a.w;
        }
        const float e2 = __expf(2.f * s);
        const float th = 1.f - 2.f / (e2 + 1.f);
        h32d[(size_t)b * NH + jb * 16 + hj] = th;
        h16d[(size_t)b * NH + jb * 16 + hj] = (f16)th;
    }
}

// ---------------------------------------------------------------------------
extern "C" void kernel_launch(void* const* d_in, const int* in_sizes, int n_in,
                              void* d_out, int out_size, void* d_ws, size_t ws_size,
                              hipStream_t stream)
{
    const float* x     = (const float*)d_in[0];
    const float* noise = (const float*)d_in[1];
    const float* Wihf  = (const float*)d_in[2];
    const float* Whhf  = (const float*)d_in[3];
    const float* bihf  = (const float*)d_in[4];
    const float* bhhf  = (const float*)d_in[5];
    const float* Wihb  = (const float*)d_in[6];
    const float* Whhb  = (const float*)d_in[7];
    const float* bihb  = (const float*)d_in[8];
    const float* bhhb  = (const float*)d_in[9];
    const float* Wmu   = (const float*)d_in[10];
    const float* bmu   = (const float*)d_in[11];
    const float* Wvar  = (const float*)d_in[12];
    const float* bvar  = (const float*)d_in[13];
    const float* Winit = (const float*)d_in[14];
    const float* binit = (const float*)d_in[15];
    const float* Wo    = (const float*)d_in[16];
    const float* bo    = (const float*)d_in[17];
    const float* Wcih  = (const float*)d_in[18];
    const float* Wchh  = (const float*)d_in[19];
    const float* bcih  = (const float*)d_in[20];
    const float* bchh  = (const float*)d_in[21];
    float* dout = (float*)d_out;
    char*  ws   = (char*)d_ws;

    if (ws_size < WS_NEEDED) return;  // ~27 MB required (unchanged)

    f16* wencp = (f16*)(ws + OFF_WENC);
    f16* wbtp  = (f16*)(ws + OFF_WBT);
    f16* wmd   = (f16*)(ws + OFF_WMD);
    f16* wnf   = (f16*)(ws + OFF_WNF);
    f16* wnb   = (f16*)(ws + OFF_WNB);
    f16* wnd   = (f16*)(ws + OFF_WND);
    f16* wo16  = (f16*)(ws + OFF_WOUT);
    f16* h16   = (f16*)(ws + OFF_HENC16);     // enc [dir][buf] / dec [4buf]
    float* hf32  = (float*)(ws + OFF_HF32);
    float* h32d  = (float*)(ws + OFF_H32D);
    float* z32p  = (float*)(ws + OFF_Z32);
    f16*   z16p  = (f16*)(ws + OFF_Z16);
    unsigned* flg_e = (unsigned*)(ws + OFF_FLG);   // enc [8][512][32]
    unsigned* flg_d = (unsigned*)(ws + OFF_CTL);   // dec [4][512][64]

    prep_kernel<<<2048, 256, 0, stream>>>(
        Whhf, Wihf, bihf, bhhf, Whhb, Wihb, bihb, bhhb,
        Wchh, Wcih, bcih, bchh, Wo, bo,
        wencp, wbtp, wmd, wnf, wnb, wnd, wo16,
        h16 /*dir0 buf0*/, h16 + (size_t)2 * NB * NH /*dir1 buf0*/,
        flg_e, flg_d);

    // encoder: 512 steps, 8 chains x 32 wide slices, coalesced B-stream
    enc_kernel<<<256, 256, 0, stream>>>(
        x, wencp, wbtp, wnf, wnb, h16, hf32, flg_e);

    heads1_kernel<<<128, 256, 0, stream>>>(hf32, hf32 + (size_t)NB * NH,
                                           Wmu, bmu, Wvar, bvar, noise,
                                           dout, z32p, z16p);
    heads2_kernel<<<64, 256, 0, stream>>>(z32p, Winit, binit, h32d, h16 /*slot 0*/);

    // decoder: 512 steps, 4 batch-chains x 64 slices, fused out-head (r13)
    persist_kernel<1><<<256, 256, 0, stream>>>(
        x, wmd, (const f16*)nullptr, wnd, (const f16*)nullptr, wo16, z16p,
        h16, (float*)nullptr, h32d, dout, flg_d);
}

// Round 11
// 8638.539 us; speedup vs baseline: 1.3246x; 1.3246x over previous
//
#include <hip/hip_runtime.h>
#include <cstdint>
#include <cstddef>

// ---------------------------------------------------------------------------
// PurifiedVAE persistent-RNN, round 17.
// r17 = r15 steady-state kernels (PROVEN: 8651 us, absmax 0.0078125) +
//       r16's division-free prep (identical values, ~2x cheaper).
// The r16 `nt` experiment is REVERTED: on gfx950, nt + sc0 sc1 demotes LLC
// residency of the h-broadcast lines (enc 4.94 -> 6.60 ms, hbm 555 -> 417
// GB/s) -- the broadcast depends on LLC hits. A-loads are sc0 sc1 only.
// enc: 256 WGs = 8 chains (2 dir x 4 batch-quarters of 64 rows) x 32 slices
//      of 32 h-cols; 48 gate-cols LDS + 48 streamed COALESCED from wbt.
// dec: persist_kernel<1>: 4 chains x 64 slices, fused out-head in slice-0,
//      quad-buffered h.
// Sync: per-WG one-shot flag slots (value = step+1), wave-parallel polling.
// ---------------------------------------------------------------------------

typedef _Float16 f16;
typedef _Float16 f16x8 __attribute__((ext_vector_type(8)));
typedef float f32x4 __attribute__((ext_vector_type(4)));

#define NB 256
#define NT 512
#define NI 12
#define NH 1024
#define NZ 128
#define NG 3072
#define KE_ENC 1056   // 1024 + 32 ext (x,1,pad)
#define KE_DEC 1184   // 1024 + 160 ext (x,1,pad,z128)
#define XK_ENC 32
#define XK_DEC 160
#define ZXP 40        // Zx row stride in halves

// wbt geometry (halves): per (dir,slice) 16*3072 chunk + 3*512 ext = 50688
#define WBT_PS 50688
#define WBT_EXT 49152

#define MFMA16(a, b, c) __builtin_amdgcn_mfma_f32_16x16x32_f16((a), (b), (c), 0, 0, 0)

// ---- workspace layout (bytes) ----
#define OFF_WENC  ((size_t)0)                              // 2*32*48*1056*2 = 6,488,064
#define OFF_WBT   (OFF_WENC + (size_t)2 * 32 * 48 * 1056 * 2)  // 2*32*50688*2 = 6,488,064
#define OFF_WMD   (OFF_WBT + (size_t)2 * 32 * WBT_PS * 2)
#define OFF_WNF   (OFF_WMD + (size_t)NG * KE_DEC * 2)
#define OFF_WNB   (OFF_WNF + (size_t)NH * XK_ENC * 2)
#define OFF_WND   (OFF_WNB + (size_t)NH * XK_ENC * 2)
#define OFF_WOUT  (OFF_WND + (size_t)NH * XK_DEC * 2)
#define OFF_HENC16 (OFF_WOUT + (size_t)16 * KE_ENC * 2)   // enc [2dir][2buf] / dec [4buf] of [NB*NH] f16
#define OFF_HF32   (OFF_HENC16 + (size_t)4 * NB * NH * 2) // [2 dir][NB*NH] f32
#define OFF_CTL    (OFF_HF32 + (size_t)2 * NB * NH * 4)   // dec flags (1 MB region)
#define OFF_H32D   (OFF_CTL + (size_t)2 * NB * NH * 2)    // [NB*NH] f32
#define OFF_Z32    (OFF_H32D + (size_t)NB * NH * 4)
#define OFF_Z16    (OFF_Z32 + (size_t)NB * NZ * 4)
#define OFF_FLG    (OFF_Z16 + (size_t)NB * NZ * 2)
#define N_FLG 204800          // enc uses first 131072 = [8][512][32]
#define N_FLGD 131072         // dec flags in CTL region: 4*512*64
#define WS_NEEDED (OFF_FLG + (size_t)N_FLG * 4)

// d_out element offsets (fp32): recon [256,512,12], mean [256,128], stddev [256,128]
#define OUT_MEAN (NB * NT * NI)
#define OUT_STD  (OUT_MEAN + NB * NZ)

// whole-wave flag poll: lanes watch nslots (power of 2) slots in parallel.
__device__ __forceinline__ void wave_spin(const unsigned* base, unsigned tgt,
                                          int lane, int nslots) {
    const unsigned* p = base + (lane & (nslots - 1));
    for (;;) {
        unsigned v = __hip_atomic_load(p, __ATOMIC_RELAXED, __HIP_MEMORY_SCOPE_AGENT);
        if (__all((int)(v == tgt))) break;
        __builtin_amdgcn_s_sleep(1);
    }
}

// counted vmcnt wait + scheduling fence (rule-18: MFMA may not hoist above).
#define PW(N) do { \
    asm volatile("s_waitcnt vmcnt(%0)" :: "n"(N) : "memory"); \
    __builtin_amdgcn_sched_barrier(0x387); \
} while (0)

// extended enc weight value at (gate-row c, k) -- same function as all rounds
__device__ __forceinline__ float enc_wval(int c, int k,
    const float* __restrict__ Whh, const float* __restrict__ Wih,
    const float* __restrict__ bih, const float* __restrict__ bhh) {
    if (k < NH) return Whh[(size_t)c * NH + k];
    const int e = k - NH;
    if (c < 2 * NH) {
        if (e < 12)  return Wih[c * 12 + e];
        if (e == 12) return bih[c] + bhh[c];
        return 0.f;
    }
    return (e == 12) ? bhh[c] : 0.f;
}

// ---------------------------------------------------------------------------
// prep: build enc compacted/transposed weights (wenc, wbt), dec extended
// weights, gi_n ext, Wout; zero h buffers + flags. Division-free row-outer
// loops (r16-proven values, identical to r15's element-stride version).
// ---------------------------------------------------------------------------
__global__ __launch_bounds__(256) void prep_kernel(
    const float* __restrict__ Whhf, const float* __restrict__ Wihf,
    const float* __restrict__ bihf, const float* __restrict__ bhhf,
    const float* __restrict__ Whhb, const float* __restrict__ Wihb,
    const float* __restrict__ bihb, const float* __restrict__ bhhb,
    const float* __restrict__ Wchh, const float* __restrict__ Wcih,
    const float* __restrict__ bcih, const float* __restrict__ bchh,
    const float* __restrict__ Wo,   const float* __restrict__ bo,
    f16* __restrict__ wenc, f16* __restrict__ wbt, f16* __restrict__ wmd,
    f16* __restrict__ wnf, f16* __restrict__ wnb, f16* __restrict__ wnd,
    f16* __restrict__ wout,
    f16* __restrict__ h16e0f, f16* __restrict__ h16e0b,
    unsigned* __restrict__ flgs, unsigned* __restrict__ flgd)
{
    const int tid = threadIdx.x;
    const int nb_ = gridDim.x;
    const int gsz = gridDim.x * blockDim.x;
    const int gid = blockIdx.x * blockDim.x + tid;

    // wenc: row-outer (3072 rows), element-inner (1056)
    for (int row = blockIdx.x; row < 2 * 32 * 48; row += nb_) {
        const int d = row / (32 * 48);
        const int rem = row - d * (32 * 48);
        const int s = rem / 48;
        const int r = rem - s * 48;
        const int c = (r >> 4) * NH + s * 32 + (r & 15);
        f16* dst = wenc + (size_t)row * 1056;
        if (d == 0)
            for (int k = tid; k < 1056; k += 256)
                dst[k] = (f16)enc_wval(c, k, Whhf, Wihf, bihf, bhhf);
        else
            for (int k = tid; k < 1056; k += 256)
                dst[k] = (f16)enc_wval(c, k, Whhb, Wihb, bihb, bhhb);
    }
    // wbt: chunk-row-outer (64 ds x 17 [16 chunks + ext]), bit-op inner
    for (int cr = blockIdx.x; cr < 64 * 17; cr += nb_) {
        const int ds = cr / 17;
        const int c = cr - ds * 17;
        const int d = ds >> 5, s = ds & 31;
        const float* Whh = d ? Whhb : Whhf;
        const float* Wih = d ? Wihb : Wihf;
        const float* bih = d ? bihb : bihf;
        const float* bhh = d ? bhhb : bhhf;
        f16* base = wbt + (size_t)ds * WBT_PS;
        if (c < 16) {
            for (int v = tid; v < 3072; v += 256) {
                const int g = v >> 10;
                const int w1 = v & 1023;
                const int kt2 = w1 >> 9;
                const int w2 = w1 & 511;
                const int l = w2 >> 3, e = w2 & 7;
                const int k = (c * 2 + kt2) * 32 + (l >> 4) * 8 + e;
                const int c_ = g * NH + s * 32 + 16 + (l & 15);
                base[c * 3072 + v] = (f16)enc_wval(c_, k, Whh, Wih, bih, bhh);
            }
        } else {
            for (int v = tid; v < 1536; v += 256) {
                const int g = v >> 9;
                const int w1 = v & 511;
                const int l = w1 >> 3, e = w1 & 7;
                const int k = 1024 + (l >> 4) * 8 + e;
                const int c_ = g * NH + s * 32 + 16 + (l & 15);
                base[WBT_EXT + v] = (f16)enc_wval(c_, k, Whh, Wih, bih, bhh);
            }
        }
    }
    // wmd: row-outer (3072 rows x 1184)
    for (int c = blockIdx.x; c < NG; c += nb_) {
        f16* dst = wmd + (size_t)c * KE_DEC;
        for (int k = tid; k < KE_DEC; k += 256) {
            float v;
            if (k < NH) v = Wchh[c * NH + k];
            else {
                const int e = k - NH;
                if (c < 2 * NH) {
                    if (e < 12)       v = Wcih[c * 140 + e];
                    else if (e == 12) v = bcih[c] + bchh[c];
                    else if (e < 32)  v = 0.f;
                    else              v = Wcih[c * 140 + 12 + (e - 32)];
                } else v = (e == 12) ? bchh[c] : 0.f;
            }
            dst[k] = (f16)v;
        }
    }
    for (int idx = gid; idx < NH * XK_ENC; idx += gsz) {
        const int j = idx >> 5, e = idx & 31;
        const int c = 2 * NH + j;
        float vf, vb;
        if (e < 12)       { vf = Wihf[c * 12 + e]; vb = Wihb[c * 12 + e]; }
        else if (e == 12) { vf = bihf[c]; vb = bihb[c]; }
        else              { vf = 0.f; vb = 0.f; }
        wnf[idx] = (f16)vf; wnb[idx] = (f16)vb;
    }
    for (int idx = gid; idx < NH * XK_DEC; idx += gsz) {
        const int j = idx / XK_DEC, e = idx - j * XK_DEC;
        const int c = 2 * NH + j;
        float v;
        if (e < 12)       v = Wcih[c * 140 + e];
        else if (e == 12) v = bcih[c];
        else if (e < 32)  v = 0.f;
        else              v = Wcih[c * 140 + 12 + (e - 32)];
        wnd[idx] = (f16)v;
    }
    for (int idx = gid; idx < 16 * KE_ENC; idx += gsz) {
        const int i = idx / KE_ENC, k = idx - i * KE_ENC;
        float v = 0.f;
        if (i < 12) {
            if (k < NH) v = Wo[i * NH + k];
            else if (k == NH + 12) v = bo[i];
        }
        wout[idx] = (f16)v;
    }
    for (int idx = gid; idx < NB * NH; idx += gsz) {
        h16e0f[idx] = (f16)0.f; h16e0b[idx] = (f16)0.f;
    }
    for (int idx = gid; idx < N_FLG; idx += gsz) flgs[idx] = 0u;
    for (int idx = gid; idx < N_FLGD; idx += gsz) flgd[idx] = 0u;
}

// ---------------------------------------------------------------------------
// enc_kernel: 256 WGs = 8 chains x 32 slices. chain = bid>>5 (dir = chain>>2,
// quarter = chain&3 -> 64-row panel); slice = bid&31 -> 32 h-cols (96 gate-
// cols: 48 in LDS + 48 streamed COALESCED from wbt). Wave owns 16 rows; A
// full-K register gather (sc0 sc1); B per-step from L2 in fragment order.
// ---------------------------------------------------------------------------
__global__ __launch_bounds__(256, 1) void enc_kernel(
    const float* __restrict__ x,
    const f16* __restrict__ wenc, const f16* __restrict__ wbt,
    const f16* __restrict__ wnF, const f16* __restrict__ wnB_,
    f16* __restrict__ hbuf,          // [dir][2][NB*NH]
    float* __restrict__ hf32,        // [dir][NB*NH]
    unsigned* __restrict__ flg)      // [8][512][32]
{
    constexpr int KE  = KE_ENC;
    constexpr int KEP = KE + 8;

    __shared__ f16 Wlds[48 * KEP];   // gates r,z,n for h-cols j0..j0+15 (102 KB)
    __shared__ f16 wnlds[32 * ZXP];  // gi_n ext weights, 32 h-cols (2.5 KB)
    __shared__ f16 Zx[64 * ZXP];     // per-step x+bias A-ext rows (5.1 KB)

    const int tid = threadIdx.x;
    const int bid = blockIdx.x;
    const int w = tid >> 6, lane = tid & 63;
    const int lr = lane & 15, quad = lane >> 4;

    const int chain = bid >> 5;          // 0..7
    const int slice = bid & 31;
    const int dir = chain >> 2;
    const int m0 = (chain & 3) * 64;
    const int j0 = slice * 32;
    const int RB = m0 + (w << 4);        // wave row base (16 rows)

    const f16* wn = dir ? wnB_ : wnF;
    f16* hb0 = hbuf + (size_t)dir * 2 * NB * NH;
    const f16* wenc_s = wenc + (size_t)(dir * 32 + slice) * 48 * 1056;
    const f16* wbt_s  = wbt  + (size_t)(dir * 32 + slice) * WBT_PS;

    // one-time LDS loads
    constexpr int KQ = KE / 8;           // 132
    for (int u = tid; u < 48 * KQ; u += 256) {
        const int r = u / KQ, kk = u - r * KQ;
        *(uint4*)&Wlds[r * KEP + kk * 8] =
            *(const uint4*)(wenc_s + (size_t)r * 1056 + kk * 8);
    }
    for (int u = tid; u < 32 * 4; u += 256) {      // gi_n ext, rows = h-col j0+r
        const int r = u >> 2, kk = u & 3;
        *(uint4*)&wnlds[r * ZXP + kk * 8] =
            *(const uint4*)(wn + (size_t)(j0 + r) * XK_ENC + kk * 8);
    }
    for (int u = tid; u < 64 * ZXP / 8; u += 256)
        *(uint4*)&Zx[u * 8] = make_uint4(0u, 0u, 0u, 0u);
    __syncthreads();

    // streamed cols' ext fragments -> registers (loaded once)
    f16x8 bext0 = *(const f16x8*)(wbt_s + WBT_EXT + 0 * 512 + lane * 8);
    f16x8 bext1 = *(const f16x8*)(wbt_s + WBT_EXT + 1 * 512 + lane * 8);
    f16x8 bext2 = *(const f16x8*)(wbt_s + WBT_EXT + 2 * 512 + lane * 8);

    // fp32 h master: [col-set][r]; rows RB+quad*4+r, cols j0+cs*16+lr
    float hmast[2][4];
#pragma unroll
    for (int cs = 0; cs < 2; ++cs)
#pragma unroll
        for (int r = 0; r < 4; ++r) hmast[cs][r] = 0.f;

    unsigned* myflg = flg + (size_t)chain * 512 * 32;

    // per-lane coalesced B base (chunk region of wbt)
    const char* vbB = (const char*)wbt_s + lane * 16;

// A chunk c = k-tiles 2c,2c+1 (2 loads, sc0 sc1 LLC-direct)
#define EA(c) do { \
    asm volatile( \
        "global_load_dwordx4 %0, %2, off offset:%3 sc0 sc1\n\t" \
        "global_load_dwordx4 %1, %2, off offset:%4 sc0 sc1" \
        : "=&v"(av[(c) & 7][0]), "=&v"(av[(c) & 7][1]) \
        : "v"(ga0), "n"((c) * 128), "n"((c) * 128 + 64) \
        : "memory"); \
} while (0)
// B chunk c: 6 COALESCED cached loads in fragment order; bv[s][g*2+kt2]
#define EB(c) do { \
    asm volatile( \
        "global_load_dwordx4 %0, %6, off offset:0\n\t" \
        "global_load_dwordx4 %1, %6, off offset:1024\n\t" \
        "global_load_dwordx4 %2, %6, off offset:2048\n\t" \
        "global_load_dwordx4 %3, %6, off offset:3072\n\t" \
        "global_load_dwordx4 %4, %7, off offset:1024\n\t" \
        "global_load_dwordx4 %5, %7, off offset:2048" \
        : "=&v"(bv[(c) & 3][0]), "=&v"(bv[(c) & 3][1]), \
          "=&v"(bv[(c) & 3][2]), "=&v"(bv[(c) & 3][3]), \
          "=&v"(bv[(c) & 3][4]), "=&v"(bv[(c) & 3][5]) \
        : "v"(vbB + (size_t)(c) * 6144), "v"(vbB + (size_t)(c) * 6144 + 3072) \
        : "memory"); \
} while (0)
#define ECONS(c) do { \
    _Pragma("unroll") \
    for (int kt2_ = 0; kt2_ < 2; ++kt2_) { \
        const int ktg_ = (c) * 2 + kt2_; \
        const f16x8 a_ = av[(c) & 7][kt2_]; \
        _Pragma("unroll") \
        for (int g_ = 0; g_ < 3; ++g_) { \
            const f16x8 bl_ = *(const f16x8*)(&Wlds[(g_ * 16 + lr) * KEP + ktg_ * 32 + (quad << 3)]); \
            acc0[g_] = MFMA16(a_, bl_, acc0[g_]); \
            acc1[g_] = MFMA16(a_, bv[(c) & 3][g_ * 2 + kt2_], acc1[g_]); \
        } \
    } \
} while (0)

#pragma unroll 1
    for (int t = 0; t < NT; ++t) {
        // stage per-step A-ext rows (x_t, bias 1 at e==12) for the 64 rows
        if (tid < 64) {
            f16 rowv[16];
            const int b_ = m0 + tid;
            const int tx = dir ? (NT - 1 - t) : t;
            const float4* xr = (const float4*)(x + ((size_t)b_ * NT + tx) * NI);
            const float4 x0 = xr[0], x1 = xr[1], x2 = xr[2];
            rowv[0] = (f16)x0.x; rowv[1] = (f16)x0.y; rowv[2] = (f16)x0.z; rowv[3] = (f16)x0.w;
            rowv[4] = (f16)x1.x; rowv[5] = (f16)x1.y; rowv[6] = (f16)x1.z; rowv[7] = (f16)x1.w;
            rowv[8] = (f16)x2.x; rowv[9] = (f16)x2.y; rowv[10] = (f16)x2.z; rowv[11] = (f16)x2.w;
            rowv[12] = (f16)1.f; rowv[13] = (f16)0.f; rowv[14] = (f16)0.f; rowv[15] = (f16)0.f;
            *(uint4*)&Zx[tid * ZXP]     = *(const uint4*)&rowv[0];
            *(uint4*)&Zx[tid * ZXP + 8] = *(const uint4*)&rowv[8];
        }
        // wait for step t-1 completion of all 32 slices (wave 0 polls)
        if (t > 0 && tid < 64)
            wave_spin(myflg + (size_t)(t - 1) * 32, (unsigned)t, lane, 32);
        __syncthreads();

        const f16* hcur = hb0 + (size_t)(t & 1) * (NB * NH);
        const char* ga0 = (const char*)(hcur + (size_t)(RB + lr) * NH) + (quad << 4);

        f32x4 acc0[3], acc1[3];
#pragma unroll
        for (int g = 0; g < 3; ++g) {
            f32x4 zv = {0.f, 0.f, 0.f, 0.f};
            acc0[g] = zv; acc1[g] = zv;
        }
        f32x4 accn0 = {0.f, 0.f, 0.f, 0.f}, accn1 = {0.f, 0.f, 0.f, 0.f};

        f16x8 av[8][2];
        f16x8 bv[4][6];
        // interleaved A/B counted-vmcnt ladder (r14/r15-verified schedule):
        EA(0); EA(1); EA(2); EA(3); EA(4);
        EB(0); EB(1); EB(2);
        PW(12); EA(5);  EB(3);  ECONS(0);
        PW(14); EA(6);  EB(4);  ECONS(1);
        PW(16); EA(7);  EB(5);  ECONS(2);
        PW(16); EA(8);  EB(6);  ECONS(3);
        PW(16); EA(9);  EB(7);  ECONS(4);
        PW(16); EA(10); EB(8);  ECONS(5);
        PW(16); EA(11); EB(9);  ECONS(6);
        PW(16); EA(12); EB(10); ECONS(7);
        PW(16); EA(13); EB(11); ECONS(8);
        PW(16); EA(14); EB(12); ECONS(9);
        PW(16); EA(15); EB(13); ECONS(10);
        PW(16); EB(14); ECONS(11);
        PW(14); EB(15); ECONS(12);
        PW(12); ECONS(13);
        PW(6);  ECONS(14);
        PW(0);  ECONS(15);

        // ext k-tile (kt=32): A = Zx (x,bias); B from Wlds / bext / wnlds
        {
            const f16x8 a0 = *(const f16x8*)(&Zx[((w << 4) + lr) * ZXP + (quad << 3)]);
            {
                const f16x8 bl = *(const f16x8*)(&Wlds[(0 * 16 + lr) * KEP + 1024 + (quad << 3)]);
                acc0[0] = MFMA16(a0, bl, acc0[0]);
                acc1[0] = MFMA16(a0, bext0, acc1[0]);
            }
            {
                const f16x8 bl = *(const f16x8*)(&Wlds[(1 * 16 + lr) * KEP + 1024 + (quad << 3)]);
                acc0[1] = MFMA16(a0, bl, acc0[1]);
                acc1[1] = MFMA16(a0, bext1, acc1[1]);
            }
            {
                const f16x8 bl = *(const f16x8*)(&Wlds[(2 * 16 + lr) * KEP + 1024 + (quad << 3)]);
                acc0[2] = MFMA16(a0, bl, acc0[2]);
                acc1[2] = MFMA16(a0, bext2, acc1[2]);
            }
            const f16x8 bn0 = *(const f16x8*)(&wnlds[lr * ZXP + (quad << 3)]);
            accn0 = MFMA16(a0, bn0, accn0);
            const f16x8 bn1 = *(const f16x8*)(&wnlds[(16 + lr) * ZXP + (quad << 3)]);
            accn1 = MFMA16(a0, bn1, accn1);
        }

        // gate combine + h update, both col-sets; packed dword write-through
        f16* hnext = hb0 + (size_t)((t + 1) & 1) * (NB * NH);
#pragma unroll
        for (int cs = 0; cs < 2; ++cs) {
#pragma unroll
            for (int r = 0; r < 4; ++r) {
                const float rr  = cs ? acc1[0][r] : acc0[0][r];
                const float zz  = cs ? acc1[1][r] : acc0[1][r];
                const float ghn = cs ? acc1[2][r] : acc0[2][r];
                const float gin = cs ? accn1[r]   : accn0[r];
                const float rg = 1.f / (1.f + __expf(-rr));
                const float zg = 1.f / (1.f + __expf(-zz));
                const float nv = gin + rg * ghn;
                const float e2 = __expf(2.f * nv);
                const float th = 1.f - 2.f / (e2 + 1.f);   // tanh, inf-safe
                const float hn = (1.f - zg) * th + zg * hmast[cs][r];
                hmast[cs][r] = hn;
                const unsigned hv =
                    (unsigned)__builtin_bit_cast(unsigned short, (f16)hn);
                const unsigned ov = (unsigned)__shfl_xor((int)hv, 1, 64);
                if (!(lr & 1)) {
                    const int row = RB + quad * 4 + r;
                    __hip_atomic_store(
                        (unsigned*)&hnext[(size_t)row * NH + j0 + cs * 16 + lr],
                        hv | (ov << 16),
                        __ATOMIC_RELAXED, __HIP_MEMORY_SCOPE_AGENT);
                }
            }
        }
        __syncthreads();   // vmcnt(0) drain of all waves' stores before flag
        if (tid == 0)
            __hip_atomic_store(myflg + (size_t)t * 32 + slice, (unsigned)(t + 1),
                               __ATOMIC_RELAXED, __HIP_MEMORY_SCOPE_AGENT);
    }
#undef EA
#undef EB
#undef ECONS

    // final fp32 h for heads1
    {
        float* hdst = hf32 + (size_t)dir * NB * NH;
#pragma unroll
        for (int cs = 0; cs < 2; ++cs)
#pragma unroll
            for (int r = 0; r < 4; ++r) {
                const int row = RB + quad * 4 + r;
                hdst[(size_t)row * NH + j0 + cs * 16 + lr] = hmast[cs][r];
            }
    }
}

// ---------------------------------------------------------------------------
// persist_kernel<MODE>: r13-verbatim structure; only MODE=1 (decoder) runs.
// dec: grid 256 = 4 chains (64 batch rows) x 64 slices; slice-0 WGs fold the
// sigmoid out-head into the gather (recon[t-1] at step t; epilogue t=511).
// ---------------------------------------------------------------------------
template<int MODE>
__global__ __launch_bounds__(256, 1) void persist_kernel(
    const float* __restrict__ x,
    const f16* __restrict__ wmF, const f16* __restrict__ wmB_,
    const f16* __restrict__ wnF, const f16* __restrict__ wnB_,
    const f16* __restrict__ wout, const f16* __restrict__ z16,
    f16* __restrict__ hbuf,          // dec: [4][NB*NH]
    float* __restrict__ hf32,
    const float* __restrict__ h32i,  // dec initial master (heads2)
    float* __restrict__ dout,
    unsigned* __restrict__ flg)      // [4][512][64]
{
    constexpr int KE  = MODE ? KE_DEC : KE_ENC;
    constexpr int KEP = KE + 8;
    constexpr int XK  = MODE ? XK_DEC : XK_ENC;
    constexpr int XKP = XK + 8;
    constexpr int NZT = MODE ? 4 : 0;   // z-register A k-tiles
    constexpr int NRT = MODE ? 1 : 2;   // row-tiles per wave
    constexpr int MROWS = MODE ? 64 : 128;  // panel rows per chain

    __shared__ f16 Wlds[48 * KEP];
    __shared__ f16 Zx[MROWS * ZXP];
    __shared__ f16 wnlds[16 * XKP];
    __shared__ f16 wolds[MODE ? 16 * 1064 : 8];  // dec: Wout (slice-0 only)

    const int tid = threadIdx.x;
    const int bid = blockIdx.x;
    const int w = tid >> 6, lane = tid & 63;
    const int lr = lane & 15, quad = lane >> 4;

    const int chain = bid >> 6;                 // 0..3
    const int slice = bid & 63;
    const int dir = MODE ? 0 : (chain >> 1);
    const int m0 = MODE ? chain * 64 : (chain & 1) * 128;
    const int j0 = slice * 16;
    const bool outw = (MODE == 1) && (slice == 0);
    const int RB = m0 + (MODE ? (w << 4) : (w << 5));

    const f16* wm = (MODE == 0 && dir) ? wmB_ : wmF;
    const f16* wn = (MODE == 0 && dir) ? wnB_ : wnF;
    f16* hb0 = hbuf + (MODE ? (size_t)0 : (size_t)dir * 2 * NB * NH);
    constexpr int BMSK = MODE ? 3 : 1;

    constexpr int KQ = KE / 8;
    for (int u = tid; u < 48 * KQ; u += 256) {
        const int r = u / KQ, kk = u - r * KQ;
        const int c = (r >> 4) * NH + j0 + (r & 15);
        *(uint4*)&Wlds[r * KEP + kk * 8] = *(const uint4*)(wm + (size_t)c * KE + kk * 8);
    }
    constexpr int XQ = XK / 8;
    for (int u = tid; u < 16 * XQ; u += 256) {
        const int r = u / XQ, kk = u - r * XQ;
        *(uint4*)&wnlds[r * XKP + kk * 8] =
            *(const uint4*)(wn + (size_t)(j0 + r) * XK + kk * 8);
    }
    if (outw) {
        for (int u = tid; u < 16 * 132; u += 256) {
            const int r = u / 132, kk = u - r * 132;
            *(uint4*)&wolds[r * 1064 + kk * 8] =
                *(const uint4*)(wout + (size_t)r * KE_ENC + kk * 8);
        }
    }
    for (int u = tid; u < MROWS * ZXP / 8; u += 256)
        *(uint4*)&Zx[u * 8] = make_uint4(0u, 0u, 0u, 0u);
    __syncthreads();

    float hmast[2][4];
    f16x8 azr[2][NZT ? NZT : 1];
#pragma unroll
    for (int rt = 0; rt < NRT; ++rt)
#pragma unroll
        for (int r = 0; r < 4; ++r)
            hmast[rt][r] = MODE
                ? h32i[(size_t)(RB + rt * 16 + quad * 4 + r) * NH + j0 + lr]
                : 0.f;
    if (MODE) {
#pragma unroll
        for (int rt = 0; rt < NRT; ++rt)
#pragma unroll
            for (int zt = 0; zt < NZT; ++zt)
                azr[rt][zt] = *(const f16x8*)(z16 +
                    (size_t)(RB + rt * 16 + lr) * NZ + zt * 32 + (quad << 3));
    }
    f16x8 ax;   // out-head A-ext: 1.0 at e==12
#pragma unroll
    for (int j = 0; j < 8; ++j) ax[j] = (f16)0.f;
    if (quad == 1) ax[4] = (f16)1.f;

    unsigned* myflg = flg + (size_t)chain * 512 * 64;

#define AISSUE_D(c) do { \
    asm volatile( \
        "global_load_dwordx4 %0, %2, off offset:%3 sc0 sc1\n\t" \
        "global_load_dwordx4 %1, %2, off offset:%4 sc0 sc1" \
        : "=&v"(av[(c)][0]), "=&v"(av[(c)][1]) \
        : "v"(ga0), "n"((c) * 128), "n"((c) * 128 + 64) \
        : "memory"); \
} while (0)
#define PCONS_D(c) do { \
    _Pragma("unroll") \
    for (int kt2_ = 0; kt2_ < 2; ++kt2_) { \
        const f16x8 a0_ = av[(c)][kt2_]; \
        _Pragma("unroll") \
        for (int g_ = 0; g_ < 3; ++g_) { \
            const f16x8 b_ = *(const f16x8*)(&Wlds[(g_ * 16 + lr) * KEP + ((c) * 2 + kt2_) * 32 + (quad << 3)]); \
            acc[g_][0] = MFMA16(a0_, b_, acc[g_][0]); \
        } \
        if (outw) { \
            const f16x8 bo_ = *(const f16x8*)(&wolds[lr * 1064 + ((c) * 2 + kt2_) * 32 + (quad << 3)]); \
            accq = MFMA16(a0_, bo_, accq); \
        } \
    } \
} while (0)
#define OCONSQ(c) do { \
    _Pragma("unroll") \
    for (int kt2_ = 0; kt2_ < 2; ++kt2_) { \
        const f16x8 bo_ = *(const f16x8*)(&wolds[lr * 1064 + ((c) * 2 + kt2_) * 32 + (quad << 3)]); \
        accq = MFMA16(av[(c)][kt2_], bo_, accq); \
    } \
} while (0)

#pragma unroll 1
    for (int t = 0; t < NT; ++t) {
        if (tid < MROWS) {
            f16 rowv[16];
            if (MODE == 1 && t == 0) {
#pragma unroll
                for (int e = 0; e < 12; ++e) rowv[e] = (f16)((e == NI - 1) ? 1.f : 0.f);
            } else {
                const int b_ = m0 + tid;
                const int tx = MODE ? (t - 1) : (dir ? (NT - 1 - t) : t);
                const float4* xr = (const float4*)(x + ((size_t)b_ * NT + tx) * NI);
                const float4 x0 = xr[0], x1 = xr[1], x2 = xr[2];
                rowv[0] = (f16)x0.x; rowv[1] = (f16)x0.y; rowv[2] = (f16)x0.z; rowv[3] = (f16)x0.w;
                rowv[4] = (f16)x1.x; rowv[5] = (f16)x1.y; rowv[6] = (f16)x1.z; rowv[7] = (f16)x1.w;
                rowv[8] = (f16)x2.x; rowv[9] = (f16)x2.y; rowv[10] = (f16)x2.z; rowv[11] = (f16)x2.w;
            }
            rowv[12] = (f16)1.f; rowv[13] = (f16)0.f; rowv[14] = (f16)0.f; rowv[15] = (f16)0.f;
            *(uint4*)&Zx[tid * ZXP]     = *(const uint4*)&rowv[0];
            *(uint4*)&Zx[tid * ZXP + 8] = *(const uint4*)&rowv[8];
        }
        if (t > 0 && tid < 64)
            wave_spin(myflg + (size_t)(t - 1) * 64, (unsigned)t, lane, 64);
        __syncthreads();

        const f16* hcur = hb0 + (size_t)(t & BMSK) * (NB * NH);
        const char* ga0 = (const char*)(hcur +
            (size_t)(RB + lr) * NH) + (quad << 4);

        f32x4 acc[3][2], accn[2];
#pragma unroll
        for (int g = 0; g < 3; ++g)
#pragma unroll
            for (int rt = 0; rt < 2; ++rt) { f32x4 zv = {0.f,0.f,0.f,0.f}; acc[g][rt] = zv; }
        { f32x4 zv = {0.f,0.f,0.f,0.f}; accn[0] = zv; accn[1] = zv; }
        f32x4 accq = {0.f, 0.f, 0.f, 0.f};

        {
            f16x8 av[16][2];
            AISSUE_D(0);  AISSUE_D(1);  AISSUE_D(2);  AISSUE_D(3);
            AISSUE_D(4);  AISSUE_D(5);  AISSUE_D(6);  AISSUE_D(7);
            AISSUE_D(8);  AISSUE_D(9);  AISSUE_D(10); AISSUE_D(11);
            AISSUE_D(12); AISSUE_D(13); AISSUE_D(14); AISSUE_D(15);
            PW(30); PCONS_D(0);
            PW(28); PCONS_D(1);
            PW(26); PCONS_D(2);
            PW(24); PCONS_D(3);
            PW(22); PCONS_D(4);
            PW(20); PCONS_D(5);
            PW(18); PCONS_D(6);
            PW(16); PCONS_D(7);
            PW(14); PCONS_D(8);
            PW(12); PCONS_D(9);
            PW(10); PCONS_D(10);
            PW(8);  PCONS_D(11);
            PW(6);  PCONS_D(12);
            PW(4);  PCONS_D(13);
            PW(2);  PCONS_D(14);
            PW(0);  PCONS_D(15);
        }

#pragma unroll
        for (int xt = 0; xt <= NZT; ++xt) {
            const int kt = 32 + xt;
            f16x8 a0, a1;
            if (xt == 0) {
                a0 = *(const f16x8*)(&Zx[((MODE ? (w << 4) : (w << 5)) + lr) * ZXP + (quad << 3)]);
                if (MODE == 0)
                    a1 = *(const f16x8*)(&Zx[((w << 5) + 16 + lr) * ZXP + (quad << 3)]);
            } else { a0 = azr[0][xt - 1]; if (NRT > 1) a1 = azr[1][xt - 1]; }
#pragma unroll
            for (int g = 0; g < 3; ++g) {
                f16x8 b = *(const f16x8*)(&Wlds[(g * 16 + lr) * KEP + kt * 32 + (quad << 3)]);
                acc[g][0] = MFMA16(a0, b, acc[g][0]);
                if (NRT > 1) acc[g][1] = MFMA16(a1, b, acc[g][1]);
            }
            f16x8 bn = *(const f16x8*)(&wnlds[lr * XKP + xt * 32 + (quad << 3)]);
            accn[0] = MFMA16(a0, bn, accn[0]);
            if (NRT > 1) accn[1] = MFMA16(a1, bn, accn[1]);
        }

        if (outw) {
            const f16x8 bo_ = *(const f16x8*)(&wolds[lr * 1064 + 1024 + (quad << 3)]);
            accq = MFMA16(ax, bo_, accq);
            if (t >= 1 && lr < NI) {
#pragma unroll
                for (int r = 0; r < 4; ++r) {
                    const int b_ = RB + quad * 4 + r;
                    dout[(size_t)b_ * (NT * NI) + (t - 1) * NI + lr] =
                        1.f / (1.f + __expf(-accq[r]));
                }
            }
        }

        f16* hnext = hb0 + (size_t)((t + 1) & BMSK) * (NB * NH);
#pragma unroll
        for (int rt = 0; rt < NRT; ++rt) {
#pragma unroll
            for (int r = 0; r < 4; ++r) {
                const float rr  = acc[0][rt][r];
                const float zz  = acc[1][rt][r];
                const float ghn = acc[2][rt][r];
                const float gin = accn[rt][r];
                const float rg = 1.f / (1.f + __expf(-rr));
                const float zg = 1.f / (1.f + __expf(-zz));
                const float nv = gin + rg * ghn;
                const float e2 = __expf(2.f * nv);
                const float th = 1.f - 2.f / (e2 + 1.f);
                const float hn = (1.f - zg) * th + zg * hmast[rt][r];
                hmast[rt][r] = hn;
                const unsigned hv =
                    (unsigned)__builtin_bit_cast(unsigned short, (f16)hn);
                const unsigned ov = (unsigned)__shfl_xor((int)hv, 1, 64);
                if (!(lr & 1)) {
                    const int row = RB + rt * 16 + quad * 4 + r;
                    __hip_atomic_store(
                        (unsigned*)&hnext[(size_t)row * NH + j0 + lr],
                        hv | (ov << 16),
                        __ATOMIC_RELAXED, __HIP_MEMORY_SCOPE_AGENT);
                }
            }
        }
        __syncthreads();
        if (tid == 0)
            __hip_atomic_store(myflg + (size_t)t * 64 + slice, (unsigned)(t + 1),
                               __ATOMIC_RELAXED, __HIP_MEMORY_SCOPE_AGENT);
    }

    if (MODE == 1 && outw) {
        if (tid < 64)
            wave_spin(myflg + (size_t)511 * 64, 512u, lane, 64);
        __syncthreads();
        const f16* hc = hb0 + (size_t)(512 & BMSK) * (NB * NH);
        const char* ga0 = (const char*)(hc + (size_t)(RB + lr) * NH) + (quad << 4);
        f32x4 accq = {0.f, 0.f, 0.f, 0.f};
        f16x8 av[16][2];
        AISSUE_D(0);  AISSUE_D(1);  AISSUE_D(2);  AISSUE_D(3);
        AISSUE_D(4);  AISSUE_D(5);  AISSUE_D(6);  AISSUE_D(7);
        AISSUE_D(8);  AISSUE_D(9);  AISSUE_D(10); AISSUE_D(11);
        AISSUE_D(12); AISSUE_D(13); AISSUE_D(14); AISSUE_D(15);
        PW(30); OCONSQ(0);
        PW(28); OCONSQ(1);
        PW(26); OCONSQ(2);
        PW(24); OCONSQ(3);
        PW(22); OCONSQ(4);
        PW(20); OCONSQ(5);
        PW(18); OCONSQ(6);
        PW(16); OCONSQ(7);
        PW(14); OCONSQ(8);
        PW(12); OCONSQ(9);
        PW(10); OCONSQ(10);
        PW(8);  OCONSQ(11);
        PW(6);  OCONSQ(12);
        PW(4);  OCONSQ(13);
        PW(2);  OCONSQ(14);
        PW(0);  OCONSQ(15);
        {
            const f16x8 bo_ = *(const f16x8*)(&wolds[lr * 1064 + 1024 + (quad << 3)]);
            accq = MFMA16(ax, bo_, accq);
        }
        if (lr < NI) {
#pragma unroll
            for (int r = 0; r < 4; ++r) {
                const int b_ = RB + quad * 4 + r;
                dout[(size_t)b_ * (NT * NI) + 511 * NI + lr] =
                    1.f / (1.f + __expf(-accq[r]));
            }
        }
    }
#undef AISSUE_D
#undef PCONS_D
#undef OCONSQ
}

// ---------------------------------------------------------------------------
// heads1: mean / stddev / z from final encoder states (fp32 exact).
// ---------------------------------------------------------------------------
__global__ __launch_bounds__(256) void heads1_kernel(
    const float* __restrict__ hf, const float* __restrict__ hb,
    const float* __restrict__ Wmu, const float* __restrict__ bmu,
    const float* __restrict__ Wvar, const float* __restrict__ bvar,
    const float* __restrict__ noise,
    float* __restrict__ dout, float* __restrict__ z32, f16* __restrict__ z16)
{
    const int tid = threadIdx.x;
    const int b  = ((int)blockIdx.x >> 3) * 16 + (tid >> 4);
    const int zi = ((int)blockIdx.x & 7) * 16 + (tid & 15);
    const float4* h4 = (const float4*)(hf + (size_t)b * NH);
    const float4* g4 = (const float4*)(hb + (size_t)b * NH);
    const float4* m4 = (const float4*)(Wmu + (size_t)zi * (2 * NH));
    const float4* v4 = (const float4*)(Wvar + (size_t)zi * (2 * NH));
    float sm_ = 0.f, sv = 0.f;
    for (int k = 0; k < NH / 4; ++k) {
        const float4 h = h4[k], a = m4[k], c = v4[k];
        sm_ += h.x * a.x + h.y * a.y + h.z * a.z + h.w * a.w;
        sv  += h.x * c.x + h.y * c.y + h.z * c.z + h.w * c.w;
    }
    for (int k = 0; k < NH / 4; ++k) {
        const float4 h = g4[k], a = m4[NH / 4 + k], c = v4[NH / 4 + k];
        sm_ += h.x * a.x + h.y * a.y + h.z * a.z + h.w * a.w;
        sv  += h.x * c.x + h.y * c.y + h.z * c.z + h.w * c.w;
    }
    const float mean = sm_ + bmu[zi];
    const float lv   = sv + bvar[zi];
    const float sd   = __expf(0.5f * lv);
    const float zv   = mean + sd * noise[(size_t)b * NZ + zi];
    dout[OUT_MEAN + (size_t)b * NZ + zi] = mean;
    dout[OUT_STD  + (size_t)b * NZ + zi] = sd;
    z32[b * NZ + zi] = zv;
    z16[b * NZ + zi] = (f16)zv;
}

// ---------------------------------------------------------------------------
// heads2: h_dec0 = tanh(z @ W_init^T + b_init) -> fp32 master + h16 buffer 0.
// ---------------------------------------------------------------------------
__global__ __launch_bounds__(256) void heads2_kernel(
    const float* __restrict__ z32, const float* __restrict__ Winit,
    const float* __restrict__ binit,
    float* __restrict__ h32d, f16* __restrict__ h16d)
{
    __shared__ float Wi[16 * NZ];
    __shared__ float bi[16];
    const int tid = threadIdx.x;
    const int jb = blockIdx.x;
    for (int f = tid; f < 16 * NZ; f += 256)
        Wi[f] = Winit[(size_t)(jb * 16 + (f >> 7)) * NZ + (f & 127)];
    if (tid < 16) bi[tid] = binit[jb * 16 + tid];
    __syncthreads();
    const int b = tid;
    const float4* z4 = (const float4*)(z32 + (size_t)b * NZ);
    float4 zr[NZ / 4];
#pragma unroll
    for (int k = 0; k < NZ / 4; ++k) zr[k] = z4[k];
    for (int hj = 0; hj < 16; ++hj) {
        const float4* w4 = (const float4*)(Wi + hj * NZ);
        float s = bi[hj];
#pragma unroll
        for (int k = 0; k < NZ / 4; ++k) {
            const float4 a = w4[k], z = zr[k];
            s += z.x * a.x + z.y * a.y + z.z * a.z + z.w * a.w;
        }
        const float e2 = __expf(2.f * s);
        const float th = 1.f - 2.f / (e2 + 1.f);
        h32d[(size_t)b * NH + jb * 16 + hj] = th;
        h16d[(size_t)b * NH + jb * 16 + hj] = (f16)th;
    }
}

// ---------------------------------------------------------------------------
extern "C" void kernel_launch(void* const* d_in, const int* in_sizes, int n_in,
                              void* d_out, int out_size, void* d_ws, size_t ws_size,
                              hipStream_t stream)
{
    const float* x     = (const float*)d_in[0];
    const float* noise = (const float*)d_in[1];
    const float* Wihf  = (const float*)d_in[2];
    const float* Whhf  = (const float*)d_in[3];
    const float* bihf  = (const float*)d_in[4];
    const float* bhhf  = (const float*)d_in[5];
    const float* Wihb  = (const float*)d_in[6];
    const float* Whhb  = (const float*)d_in[7];
    const float* bihb  = (const float*)d_in[8];
    const float* bhhb  = (const float*)d_in[9];
    const float* Wmu   = (const float*)d_in[10];
    const float* bmu   = (const float*)d_in[11];
    const float* Wvar  = (const float*)d_in[12];
    const float* bvar  = (const float*)d_in[13];
    const float* Winit = (const float*)d_in[14];
    const float* binit = (const float*)d_in[15];
    const float* Wo    = (const float*)d_in[16];
    const float* bo    = (const float*)d_in[17];
    const float* Wcih  = (const float*)d_in[18];
    const float* Wchh  = (const float*)d_in[19];
    const float* bcih  = (const float*)d_in[20];
    const float* bchh  = (const float*)d_in[21];
    float* dout = (float*)d_out;
    char*  ws   = (char*)d_ws;

    if (ws_size < WS_NEEDED) return;  // ~27 MB required (unchanged)

    f16* wencp = (f16*)(ws + OFF_WENC);
    f16* wbtp  = (f16*)(ws + OFF_WBT);
    f16* wmd   = (f16*)(ws + OFF_WMD);
    f16* wnf   = (f16*)(ws + OFF_WNF);
    f16* wnb   = (f16*)(ws + OFF_WNB);
    f16* wnd   = (f16*)(ws + OFF_WND);
    f16* wo16  = (f16*)(ws + OFF_WOUT);
    f16* h16   = (f16*)(ws + OFF_HENC16);     // enc [dir][buf] / dec [4buf]
    float* hf32  = (float*)(ws + OFF_HF32);
    float* h32d  = (float*)(ws + OFF_H32D);
    float* z32p  = (float*)(ws + OFF_Z32);
    f16*   z16p  = (f16*)(ws + OFF_Z16);
    unsigned* flg_e = (unsigned*)(ws + OFF_FLG);   // enc [8][512][32]
    unsigned* flg_d = (unsigned*)(ws + OFF_CTL);   // dec [4][512][64]

    prep_kernel<<<2048, 256, 0, stream>>>(
        Whhf, Wihf, bihf, bhhf, Whhb, Wihb, bihb, bhhb,
        Wchh, Wcih, bcih, bchh, Wo, bo,
        wencp, wbtp, wmd, wnf, wnb, wnd, wo16,
        h16 /*dir0 buf0*/, h16 + (size_t)2 * NB * NH /*dir1 buf0*/,
        flg_e, flg_d);

    // encoder: 512 steps, 8 chains x 32 wide slices, coalesced B-stream
    enc_kernel<<<256, 256, 0, stream>>>(
        x, wencp, wbtp, wnf, wnb, h16, hf32, flg_e);

    heads1_kernel<<<128, 256, 0, stream>>>(hf32, hf32 + (size_t)NB * NH,
                                           Wmu, bmu, Wvar, bvar, noise,
                                           dout, z32p, z16p);
    heads2_kernel<<<64, 256, 0, stream>>>(z32p, Winit, binit, h32d, h16 /*slot 0*/);

    // decoder: 512 steps, 4 batch-chains x 64 slices, fused out-head (r13)
    persist_kernel<1><<<256, 256, 0, stream>>>(
        x, wmd, (const f16*)nullptr, wnd, (const f16*)nullptr, wo16, z16p,
        h16, (float*)nullptr, h32d, dout, flg_d);
}